// Round 4
// baseline (318.461 us; speedup 1.0000x reference)
//
#include <hip/hip_runtime.h>
#include <math.h>

// Problem constants
#define NCELLS 131072
#define IND 64
#define HD 128
#define OUTD 64
#define NF 8
#define FS 16384
#define DC 4096
#define TB 64             // cells per fused block
#define NBLK (NCELLS/TB)  // 2048
#define NTH 512

typedef __bf16 bf16x8 __attribute__((ext_vector_type(8)));
typedef float f32x4 __attribute__((ext_vector_type(4)));
typedef unsigned short us8 __attribute__((ext_vector_type(8)));

#define MFMA(a,b,c) __builtin_amdgcn_mfma_f32_16x16x32_bf16(a,b,c,0,0,0)

// ---- workspace layout ----
// ushort (bf16) region:
#define WS_W1F 0          // [256][192]  fused [W1a;W1g]
#define WS_W2F 49152      // [64][256]   fused [W2a | -W2g]
#define WS_WIH 65536      // [384][96]   Wih padded K 65->96 with zeros
#define WS_WHH 102400     // [384][128]
#define WS_U_TOTAL 151552
// float region at (float*)((ushort*)ws + WS_U_TOTAL):
#define WF_B1   0         // [256]
#define WF_B2   256       // [64]
#define WF_FSUM 320       // [8][128]
#define WF_WSUM 1344      // [64]
#define WF_SE   1408
#define WF_TS   1409
// bf16 h_pre scratch (32MB) at byte offset:
#define WS_NH_OFF 308992

// ---- LDS layout (ushort units), total 17472 us = 34944 B -> 4 blocks/CU ----
#define L_SX   0          // [64] us      : x bf16 (shared across all cells)
#define L_SH   64         // [64][136] us : h tile bf16 (cols 0..127) ; reused as h_pre staging
#define L_H1   8768       // [64][136] us : h1 half bf16 ; overlaid after phase 2 by:
#define L_SOB  8768       //   [64][104] us : [out|t|0pad] bf16
#define F_STP  7712       //   float idx: t-partials [4][64]
#define F_ST   7968       //   float idx: t [64]
#define F_SE   8032       //   float idx: e^t [64]
#define L_TOT  17472

__device__ __forceinline__ unsigned short f2bf(float f) {
    unsigned u = __builtin_bit_cast(unsigned, f);
    return (unsigned short)((u + 0x7FFFu + ((u >> 16) & 1u)) >> 16);
}
__device__ __forceinline__ float bf2f(unsigned short h) {
    return __builtin_bit_cast(float, (unsigned)h << 16);
}
__device__ __forceinline__ bf16x8 ld8(const unsigned short* p) {
    return __builtin_bit_cast(bf16x8, *(const us8*)p);
}
__device__ __forceinline__ float sigm(float v) { return 1.f/(1.f + __expf(-v)); }
__device__ __forceinline__ float ftanh(float v) {
    float e = __expf(-2.f*v);          // inf-safe: 2/(1+inf)-1 = -1, 2/(1+0)-1 = 1
    return 2.f/(1.f + e) - 1.f;
}

// ---- per-launch weight conversion fp32 -> bf16 (+ accumulator zeroing) ----
__global__ __launch_bounds__(256) void convert_kernel(
    const float* __restrict__ W1a, const float* __restrict__ b1a,
    const float* __restrict__ W2a, const float* __restrict__ b2a,
    const float* __restrict__ W1g, const float* __restrict__ b1g,
    const float* __restrict__ W2g, const float* __restrict__ b2g,
    const float* __restrict__ Wih, const float* __restrict__ Whh,
    unsigned short* __restrict__ wsu, float* __restrict__ wsf)
{
    int i = blockIdx.x * 256 + threadIdx.x;
    if (i < 49152) {                       // W1f = [W1a ; W1g]
        int r = i / 192, k = i - r*192;
        float v = (r < 128) ? W1a[r*192 + k] : W1g[(r-128)*192 + k];
        wsu[WS_W1F + i] = f2bf(v); return;
    }
    int j = i - 49152;
    if (j < 16384) {                       // W2f = [W2a | -W2g]
        int r = j >> 8, k = j & 255;
        float v = (k < 128) ? W2a[r*128 + k] : -W2g[r*128 + (k-128)];
        wsu[WS_W2F + j] = f2bf(v); return;
    }
    j -= 16384;
    if (j < 36864) {                       // Wih padded to K=96
        int r = j / 96, k = j - r*96;
        float v = (k < 65) ? Wih[r*65 + k] : 0.f;
        wsu[WS_WIH + j] = f2bf(v); return;
    }
    j -= 36864;
    if (j < 49152) { wsu[WS_WHH + j] = f2bf(Whh[j]); return; }
    j -= 49152;
    if (j < 256) { wsf[WF_B1 + j] = (j < 128) ? b1a[j] : b1g[j-128]; return; }
    j -= 256;
    if (j < 64)  { wsf[WF_B2 + j] = b2a[j] - b2g[j]; return; }
    j -= 64;
    if (j < NF*HD + OUTD + 2) { wsf[WF_FSUM + j] = 0.f; return; }   // zero accumulators
}

// ---- fused per-cell pipeline, bf16 MFMA, TB=64, 8 waves, ~35KB LDS ----
__global__ __launch_bounds__(NTH, 6) void fused_cell_kernel(
    const float* __restrict__ x, const float* __restrict__ hiddens,
    const float* __restrict__ bih, const float* __restrict__ bhh,
    const unsigned short* __restrict__ wsu, const float* __restrict__ wsf,
    unsigned short* __restrict__ nh, float* __restrict__ fsum,
    float* __restrict__ wsum, float* __restrict__ sumexp, float* __restrict__ tsum)
{
    __shared__ __align__(16) unsigned short sm[L_TOT];
    float* smf = (float*)sm;

    const int tid = threadIdx.x;
    const int cell0 = blockIdx.x * TB;
    const int w = tid >> 6, lane = tid & 63;
    const int q = lane >> 4, cL = lane & 15;

    // ---- phase 0: stage x once + h tile bf16 ----
    if (tid < 64) sm[L_SX + tid] = f2bf(x[tid]);
    for (int idx = tid; idx < TB*32; idx += NTH) {        // 2048 float4 loads
        int c = idx >> 5, k4 = idx & 31;
        float4 v = ((const float4*)hiddens)[(size_t)(cell0+c)*32 + k4];
        unsigned p0 = (unsigned)f2bf(v.x) | ((unsigned)f2bf(v.y) << 16);
        unsigned p1 = (unsigned)f2bf(v.z) | ((unsigned)f2bf(v.w) << 16);
        uint2 pp = {p0, p1};
        *(uint2*)&sm[L_SH + c*136 + k4*4] = pp;
    }
    __syncthreads();

    // ---- phases 1&2: two K-halves of GEMM1 (h1 half in LDS) + GEMM2 partials ----
    const int col2 = (w & 3)*16 + cL;       // GEMM2 output col 0..63
    const int Mh = w >> 2;                  // GEMM2 M-half (cells Mh*32..Mh*32+31)
    f32x4 o0, o1;
    {
        const float b2 = wsf[WF_B2 + col2];
        o0 = (f32x4){b2,b2,b2,b2}; o1 = o0;
    }
    #pragma unroll
    for (int g = 0; g < 2; ++g) {
        // GEMM1 half g: h1 cols g*128..g*128+127 -> L_H1 cols 0..127
        {
            const int col = w*16 + cL;                    // 0..127
            const float bias = wsf[WF_B1 + g*128 + col];
            f32x4 acc[4];
            #pragma unroll
            for (int m = 0; m < 4; ++m) acc[m] = (f32x4){bias,bias,bias,bias};
            const unsigned short* wp = wsu + WS_W1F + (size_t)(g*128 + col)*192 + q*8;
            #pragma unroll
            for (int kb = 0; kb < 2; ++kb) {              // x part: broadcast A
                bf16x8 B = ld8(wp + kb*32);
                bf16x8 A = ld8(&sm[L_SX + kb*32 + q*8]);
                #pragma unroll
                for (int m = 0; m < 4; ++m) acc[m] = MFMA(A, B, acc[m]);
            }
            #pragma unroll
            for (int kb = 0; kb < 4; ++kb) {              // h part
                bf16x8 B = ld8(wp + 64 + kb*32);
                #pragma unroll
                for (int m = 0; m < 4; ++m) {
                    bf16x8 A = ld8(&sm[L_SH + (m*16+cL)*136 + kb*32 + q*8]);
                    acc[m] = MFMA(A, B, acc[m]);
                }
            }
            #pragma unroll
            for (int m = 0; m < 4; ++m)
                #pragma unroll
                for (int r = 0; r < 4; ++r)
                    sm[L_H1 + (m*16+q*4+r)*136 + col] = f2bf(fmaxf(acc[m][r], 0.f));
        }
        __syncthreads();
        // GEMM2 partial: K = g*128..g*128+127
        {
            const unsigned short* wp = wsu + WS_W2F + (size_t)col2*256 + g*128 + q*8;
            #pragma unroll
            for (int kb = 0; kb < 4; ++kb) {
                bf16x8 B  = ld8(wp + kb*32);
                bf16x8 A0 = ld8(&sm[L_H1 + (Mh*32   +cL)*136 + kb*32 + q*8]);
                bf16x8 A1 = ld8(&sm[L_H1 + (Mh*32+16+cL)*136 + kb*32 + q*8]);
                o0 = MFMA(A0, B, o0);
                o1 = MFMA(A1, B, o1);
            }
        }
        __syncthreads();   // g=0: before h1 reuse; g=1: before sob overlay writes
    }

    // ---- t-partials in registers (sum of out^2 over this wave's 16 cols) ----
    float p0r[4], p1r[4];
    #pragma unroll
    for (int r = 0; r < 4; ++r) {
        float s0 = o0[r]*o0[r], s1 = o1[r]*o1[r];
        s0 += __shfl_xor(s0, 1); s1 += __shfl_xor(s1, 1);
        s0 += __shfl_xor(s0, 2); s1 += __shfl_xor(s1, 2);
        s0 += __shfl_xor(s0, 4); s1 += __shfl_xor(s1, 4);
        s0 += __shfl_xor(s0, 8); s1 += __shfl_xor(s1, 8);
        p0r[r] = s0; p1r[r] = s1;
    }

    // ---- phase 2c: write sob (bf16 out), stp, zero gi pad cols ----
    #pragma unroll
    for (int r = 0; r < 4; ++r) {
        const int r0 = Mh*32 + q*4 + r, r1 = r0 + 16;
        sm[L_SOB + r0*104 + col2] = f2bf(o0[r]);
        sm[L_SOB + r1*104 + col2] = f2bf(o1[r]);
    }
    if (cL == 0) {
        const int ct = w & 3;
        #pragma unroll
        for (int r = 0; r < 4; ++r) {
            smf[F_STP + ct*64 + (Mh*32 + q*4 + r)]      = p0r[r];
            smf[F_STP + ct*64 + (Mh*32 + 16 + q*4 + r)] = p1r[r];
        }
    }
    for (int idx = tid; idx < TB*32; idx += NTH) {        // sob cols 64..95 = 0
        int c = idx >> 5, k = idx & 31;
        sm[L_SOB + c*104 + 64 + k] = 0;
    }
    __syncthreads();

    // ---- phase 3: t, e^t ----
    if (tid < TB) {
        float t = (smf[F_STP+tid] + smf[F_STP+64+tid] + smf[F_STP+128+tid]
                 + smf[F_STP+192+tid]) * (1.0f/OUTD);
        smf[F_ST + tid] = t;
        smf[F_SE + tid] = __expf(t);
        sm[L_SOB + tid*104 + 64] = f2bf(t);
    }
    __syncthreads();

    // ---- phase 5 (early): softmax-weighted sums ----
    if (tid < OUTD) {
        float wacc = 0.f;
        #pragma unroll 4
        for (int c = 0; c < TB; ++c) wacc += smf[F_SE + c] * bf2f(sm[L_SOB + c*104 + tid]);
        unsafeAtomicAdd(&wsum[tid], wacc);
    }
    if (tid == 0) {
        float sE = 0.f, sT = 0.f;
        #pragma unroll 4
        for (int c = 0; c < TB; ++c) { sE += smf[F_SE + c]; sT += smf[F_ST + c]; }
        unsafeAtomicAdd(sumexp, sE);
        unsafeAtomicAdd(tsum, sT);
    }

    // ---- phase 4: GRU gates (MFMA) + transposed epilogue through LDS ----
    const int f = (int)(blockIdx.x >> 8);     // 256 blocks per faction
    const int j = w*16 + cL;                  // hidden unit for this lane
    const float bR = bih[j]      + bhh[j];
    const float bZ = bih[HD+j]   + bhh[HD+j];
    const float bI = bih[2*HD+j];
    const float bH = bhh[2*HD+j];
    float colsum = 0.f;
    #pragma unroll
    for (int h = 0; h < 2; ++h) {
        f32x4 R0 = {bR,bR,bR,bR}, R1 = R0;
        f32x4 Z0 = {bZ,bZ,bZ,bZ}, Z1 = Z0;
        f32x4 I0 = {bI,bI,bI,bI}, I1 = I0;
        f32x4 H0 = {bH,bH,bH,bH}, H1 = H0;
        const unsigned short* wi = wsu + WS_WIH + q*8;
        #pragma unroll
        for (int k = 0; k < 3; ++k) {         // gi: A=[out|t|0], K=96
            bf16x8 Br = ld8(wi + (size_t)j*96        + k*32);
            bf16x8 Bz = ld8(wi + (size_t)(HD+j)*96   + k*32);
            bf16x8 Bi = ld8(wi + (size_t)(2*HD+j)*96 + k*32);
            bf16x8 A0 = ld8(&sm[L_SOB + (h*32   +cL)*104 + k*32 + q*8]);
            bf16x8 A1 = ld8(&sm[L_SOB + (h*32+16+cL)*104 + k*32 + q*8]);
            R0 = MFMA(A0, Br, R0); R1 = MFMA(A1, Br, R1);
            Z0 = MFMA(A0, Bz, Z0); Z1 = MFMA(A1, Bz, Z1);
            I0 = MFMA(A0, Bi, I0); I1 = MFMA(A1, Bi, I1);
        }
        const unsigned short* wh = wsu + WS_WHH + q*8;
        #pragma unroll
        for (int k = 0; k < 4; ++k) {         // gh: A=h, K=128
            bf16x8 Br = ld8(wh + (size_t)j*128        + k*32);
            bf16x8 Bz = ld8(wh + (size_t)(HD+j)*128   + k*32);
            bf16x8 Bn = ld8(wh + (size_t)(2*HD+j)*128 + k*32);
            bf16x8 A0 = ld8(&sm[L_SH + (h*32   +cL)*136 + k*32 + q*8]);
            bf16x8 A1 = ld8(&sm[L_SH + (h*32+16+cL)*136 + k*32 + q*8]);
            R0 = MFMA(A0, Br, R0); R1 = MFMA(A1, Br, R1);
            Z0 = MFMA(A0, Bz, Z0); Z1 = MFMA(A1, Bz, Z1);
            H0 = MFMA(A0, Bn, H0); H1 = MFMA(A1, Bn, H1);
        }
        float hv0[4], hv1[4];
        #pragma unroll
        for (int r = 0; r < 4; ++r) {
            int row0 = h*32 + q*4 + r, row1 = row0 + 16;
            float rr = sigm(R0[r]), zz = sigm(Z0[r]);
            float nn = ftanh(I0[r] + rr*H0[r]);
            float hold = bf2f(sm[L_SH + row0*136 + j]);
            hv0[r] = (1.f - zz)*nn + zz*hold;  colsum += hv0[r];
            rr = sigm(R1[r]); zz = sigm(Z1[r]);
            nn = ftanh(I1[r] + rr*H1[r]);
            hold = bf2f(sm[L_SH + row1*136 + j]);
            hv1[r] = (1.f - zz)*nn + zz*hold;  colsum += hv1[r];
        }
        __syncthreads();      // all reads of L_SH rows h*32..h*32+31 complete
        #pragma unroll
        for (int r = 0; r < 4; ++r) {
            int row0 = h*32 + q*4 + r, row1 = row0 + 16;
            sm[L_SH + row0*136 + j] = f2bf(hv0[r]);
            sm[L_SH + row1*136 + j] = f2bf(hv1[r]);
        }
        __syncthreads();      // staging visible
        {                     // contiguous store: 512 threads x one us8 (16B) = 8KB/half
            const int c_l = tid >> 4, k8 = tid & 15;
            const int row = h*32 + c_l;
            us8 v = *(const us8*)&sm[L_SH + row*136 + k8*8];
            *(us8*)&nh[(size_t)(cell0 + row)*HD + k8*8] = v;
        }
    }
    colsum += __shfl_xor(colsum, 16);
    colsum += __shfl_xor(colsum, 32);
    if (q == 0) unsafeAtomicAdd(&fsum[f*HD + j], colsum);
}

// ---- faction sync: dst = a*src + b[j]  (src bf16 scratch, dst fp32 d_out) ----
#define FTB 128
__global__ __launch_bounds__(256) void faction_kernel(
    const unsigned short* __restrict__ src, float* __restrict__ dst,
    const float* __restrict__ fsum, const int* __restrict__ step)
{
    __shared__ float brow[HD];
    const int f = blockIdx.x >> 7;            // 128 blocks per faction
    const size_t base = (size_t)blockIdx.x * FTB * HD;
    const bool debate = (step[0] > 5) && (((blockIdx.x * FTB) & (FS-1)) < DC);
    if (threadIdx.x < HD) {
        const int jj = threadIdx.x;
        float s = 0.f;
        #pragma unroll
        for (int ff = 0; ff < NF; ++ff) s += fsum[ff*HD + jj];
        const float go = s * (1.0f/NCELLS);
        const float fm = fsum[f*HD + jj] * (1.0f/FS);
        brow[jj] = debate ? (0.1275f*fm + 0.15f*go) : (0.15f*fm);
    }
    __syncthreads();
    const float a = debate ? 0.7225f : 0.85f;
    const int w = threadIdx.x >> 6, lane = threadIdx.x & 63;
    #pragma unroll 8
    for (int i = 0; i < 64; ++i) {
        const int idx = w*4096 + i*64 + lane;     // 256B-contiguous wave stores
        const float v = bf2f(src[base + idx]);
        dst[base + idx] = a*v + brow[idx & 127];
    }
}

__global__ void final_kernel(const float* __restrict__ Wo, const float* __restrict__ bo,
                             const float* __restrict__ wsum, const float* __restrict__ sumexp,
                             const float* __restrict__ tsum, float* __restrict__ d_out)
{
    const int i = threadIdx.x;
    if (i < OUTD) {
        const float inv = 1.0f / sumexp[0];
        const float* wr = Wo + (size_t)i*OUTD;
        float acc = bo[i];
        for (int jj = 0; jj < OUTD; ++jj) acc += (wsum[jj]*inv) * wr[jj];
        d_out[i] = acc;
    }
    if (i == 0) d_out[OUTD] = tsum[0] * (1.0f/NCELLS);
}

extern "C" void kernel_launch(void* const* d_in, const int* in_sizes, int n_in,
                              void* d_out, int out_size, void* d_ws, size_t ws_size,
                              hipStream_t stream)
{
    const float* x   = (const float*)d_in[0];
    const float* hid = (const float*)d_in[1];
    const float* W1a = (const float*)d_in[2];
    const float* b1a = (const float*)d_in[3];
    const float* W2a = (const float*)d_in[4];
    const float* b2a = (const float*)d_in[5];
    const float* W1g = (const float*)d_in[6];
    const float* b1g = (const float*)d_in[7];
    const float* W2g = (const float*)d_in[8];
    const float* b2g = (const float*)d_in[9];
    const float* Wih = (const float*)d_in[10];
    const float* Whh = (const float*)d_in[11];
    const float* bih = (const float*)d_in[12];
    const float* bhh = (const float*)d_in[13];
    const float* Wo  = (const float*)d_in[14];
    const float* bo  = (const float*)d_in[15];
    const int*  step = (const int*)d_in[16];

    float* out  = (float*)d_out;
    float* newh_out = out + (OUTD + 1);

    unsigned short* wsu = (unsigned short*)d_ws;
    float* wsf = (float*)(wsu + WS_U_TOTAL);
    float* fsum   = wsf + WF_FSUM;
    float* wsum   = wsf + WF_WSUM;
    float* sumexp = wsf + WF_SE;
    float* tsum   = wsf + WF_TS;
    unsigned short* nh = (unsigned short*)((char*)d_ws + WS_NH_OFF);  // bf16 h_pre, 32MB

    // convert also zeroes the accumulator slice (ws re-poisoned each launch)
    const int conv_n = WS_U_TOTAL + 256 + 64 + (NF*HD + OUTD + 2);
    convert_kernel<<<(conv_n + 255)/256, 256, 0, stream>>>(
        W1a, b1a, W2a, b2a, W1g, b1g, W2g, b2g, Wih, Whh, wsu, wsf);

    fused_cell_kernel<<<NBLK, NTH, 0, stream>>>(
        x, hid, bih, bhh, wsu, wsf, nh, fsum, wsum, sumexp, tsum);

    faction_kernel<<<NCELLS/FTB, 256, 0, stream>>>(nh, newh_out, fsum, step);

    final_kernel<<<1, 64, 0, stream>>>(Wo, bo, wsum, sumexp, tsum, out);
}